// Round 1
// baseline (556.238 us; speedup 1.0000x reference)
//
#include <hip/hip_runtime.h>
#include <hip/hip_bf16.h>
#include <hip/hip_fp16.h>

#define B_ 8
#define S_ 2048
#define D_ 512

typedef _Float16 f16x8 __attribute__((ext_vector_type(8)));
typedef float f32x4 __attribute__((ext_vector_type(4)));

// ---------------------------------------------------------------------------
// Kernel 1: convert W (fp32, [k][n]) -> W^T (fp16, [n][k]) so that MFMA
// B-fragments (8 consecutive k at fixed n) are contiguous 16B loads.
// ---------------------------------------------------------------------------
__global__ void wconv_kernel(const float* __restrict__ Wq,
                             const float* __restrict__ Wk,
                             const float* __restrict__ Wv,
                             _Float16* __restrict__ w_ws) {
    int idx = blockIdx.x * 256 + threadIdx.x;       // 0 .. 512*512-1
    int which = blockIdx.y;
    const float* W = (which == 0) ? Wq : (which == 1) ? Wk : Wv;
    int n = idx >> 9;
    int k = idx & 511;
    w_ws[(size_t)which * D_ * D_ + (size_t)n * D_ + k] = (_Float16)W[(size_t)k * D_ + n];
}

// ---------------------------------------------------------------------------
// Kernel 2: projection GEMM  C = X @ W + b  (M=16384, N=512, K=512), fp16 out.
// Block: 256 thr (4 waves), tile 128x128; wave w owns rows w*32..+31 x all 128 cols.
// which==2 (v) is stored transposed: v_ws[b][d][s].
// ---------------------------------------------------------------------------
__launch_bounds__(256)
__global__ void proj_kernel(const float* __restrict__ Q,
                            const float* __restrict__ K,
                            const float* __restrict__ V,
                            const _Float16* __restrict__ w_ws,
                            const float* __restrict__ bq,
                            const float* __restrict__ bk,
                            const float* __restrict__ bv,
                            _Float16* __restrict__ q_ws,
                            _Float16* __restrict__ k_ws,
                            _Float16* __restrict__ v_ws) {
    const int which = blockIdx.z;
    const float* X    = (which == 0) ? Q  : (which == 1) ? K  : V;
    const float* bias = (which == 0) ? bq : (which == 1) ? bk : bv;
    const _Float16* Wt = w_ws + (size_t)which * D_ * D_;

    const int Mb = blockIdx.x * 128;   // 128 M-tiles
    const int Nb = blockIdx.y * 128;   // 4 N-tiles
    const int t = threadIdx.x;
    const int w = t >> 6;              // wave 0..3
    const int l = t & 63;
    const int lr = l & 15;             // fragment row/col
    const int lk = (l >> 4) * 8;       // fragment k-offset
    const int lq = (l >> 4) * 4;       // C-fragment row base

    f32x4 acc[2][8] = {};

    for (int k0 = 0; k0 < D_; k0 += 32) {
        f16x8 a[2], bfr[8];
#pragma unroll
        for (int mi = 0; mi < 2; mi++) {
            int row = Mb + w * 32 + mi * 16 + lr;
            const float* p = X + (size_t)row * D_ + k0 + lk;
            float xa[8];
            *(float4*)&xa[0] = *(const float4*)p;
            *(float4*)&xa[4] = *(const float4*)(p + 4);
#pragma unroll
            for (int j = 0; j < 8; j++) a[mi][j] = (_Float16)xa[j];
        }
#pragma unroll
        for (int ni = 0; ni < 8; ni++) {
            int col = Nb + ni * 16 + lr;
            bfr[ni] = *(const f16x8*)(Wt + (size_t)col * D_ + k0 + lk);
        }
#pragma unroll
        for (int mi = 0; mi < 2; mi++)
#pragma unroll
            for (int ni = 0; ni < 8; ni++)
                acc[mi][ni] = __builtin_amdgcn_mfma_f32_16x16x32_f16(a[mi], bfr[ni], acc[mi][ni], 0, 0, 0);
    }

    // epilogue: + bias, cast fp16, store (v transposed)
#pragma unroll
    for (int ni = 0; ni < 8; ni++) {
        int col = Nb + ni * 16 + lr;
        float bn = bias[col];
#pragma unroll
        for (int mi = 0; mi < 2; mi++) {
#pragma unroll
            for (int j = 0; j < 4; j++) {
                int row = Mb + w * 32 + mi * 16 + lq + j;
                float vv = acc[mi][ni][j] + bn;
                if (which == 0) {
                    q_ws[(size_t)row * D_ + col] = (_Float16)vv;
                } else if (which == 1) {
                    k_ws[(size_t)row * D_ + col] = (_Float16)vv;
                } else {
                    int bb = row >> 11, s = row & 2047;
                    v_ws[((size_t)bb * D_ + col) * S_ + s] = (_Float16)vv;
                }
            }
        }
    }
}

// ---------------------------------------------------------------------------
// Kernel 3: flash attention (unscaled softmax). QBLK=64, KVBLK=128.
// 512 thr = 8 waves = 2 q-groups x 4 chunk-groups. Online softmax in LDS.
// ---------------------------------------------------------------------------
__launch_bounds__(512)
__global__ void attn_kernel(const _Float16* __restrict__ q_ws,
                            const _Float16* __restrict__ k_ws,
                            const _Float16* __restrict__ v_ws,
                            float* __restrict__ out) {
    __shared__ float    S_lds[64][132];     // padded: 132 floats/row
    __shared__ _Float16 P_lds[64][136];     // padded: 272B rows (16B aligned)
    __shared__ float    m_lds[64];
    __shared__ float    l_lds[64];
    __shared__ float    alpha_lds[64];

    const int bid = blockIdx.x;
    const int b  = bid & 7;        // batch -> XCD affinity (K/V L2 residency)
    const int qb = (bid >> 3) * 64;

    const int t = threadIdx.x;
    const int w = t >> 6;
    const int l = t & 63;
    const int qg = w >> 2;         // 0..1 : q-row group (32 rows)
    const int kc = w & 3;          // 0..3 : kv-chunk (QK^T) / d-chunk (PV)
    const int lr = l & 15;
    const int lk = (l >> 4) * 8;
    const int lq = (l >> 4) * 4;

    const _Float16* qp = q_ws + (size_t)b * S_ * D_;
    const _Float16* kp = k_ws + (size_t)b * S_ * D_;
    const _Float16* vp = v_ws + (size_t)b * D_ * S_;

    if (t < 64) { m_lds[t] = -INFINITY; l_lds[t] = 0.f; }

    f32x4 oacc[2][8] = {};
    __syncthreads();

    for (int kv0 = 0; kv0 < S_; kv0 += 128) {
        // ---- QK^T: wave (qg,kc) computes S[qg*32..+32][kc*32..+32] over D=512
        f32x4 sacc[2][2] = {};
        for (int d0 = 0; d0 < D_; d0 += 32) {
            f16x8 aq[2], bk2[2];
#pragma unroll
            for (int mi = 0; mi < 2; mi++)
                aq[mi] = *(const f16x8*)(qp + (size_t)(qb + qg * 32 + mi * 16 + lr) * D_ + d0 + lk);
#pragma unroll
            for (int ni = 0; ni < 2; ni++)
                bk2[ni] = *(const f16x8*)(kp + (size_t)(kv0 + kc * 32 + ni * 16 + lr) * D_ + d0 + lk);
#pragma unroll
            for (int mi = 0; mi < 2; mi++)
#pragma unroll
                for (int ni = 0; ni < 2; ni++)
                    sacc[mi][ni] = __builtin_amdgcn_mfma_f32_16x16x32_f16(aq[mi], bk2[ni], sacc[mi][ni], 0, 0, 0);
        }
#pragma unroll
        for (int mi = 0; mi < 2; mi++)
#pragma unroll
            for (int ni = 0; ni < 2; ni++)
#pragma unroll
                for (int j = 0; j < 4; j++)
                    S_lds[qg * 32 + mi * 16 + lq + j][kc * 32 + ni * 16 + lr] = sacc[mi][ni][j];
        __syncthreads();

        // ---- online softmax: 8 threads per row (64 rows x 128 cols)
        {
            const int r = t >> 3;
            const int cs = (t & 7) * 16;
            float sv[16];
#pragma unroll
            for (int c4 = 0; c4 < 4; c4++)
                *(float4*)&sv[c4 * 4] = *(const float4*)&S_lds[r][cs + c4 * 4];
            float mx = sv[0];
#pragma unroll
            for (int c = 1; c < 16; c++) mx = fmaxf(mx, sv[c]);
            mx = fmaxf(mx, __shfl_xor(mx, 1));
            mx = fmaxf(mx, __shfl_xor(mx, 2));
            mx = fmaxf(mx, __shfl_xor(mx, 4));
            float m_old = m_lds[r];
            float m_new = fmaxf(m_old, mx);
            float ps = 0.f;
            f16x8 p0, p1;
#pragma unroll
            for (int c = 0; c < 8; c++) {
                float p = __expf(sv[c] - m_new);
                ps += p;
                p0[c] = (_Float16)p;
            }
#pragma unroll
            for (int c = 0; c < 8; c++) {
                float p = __expf(sv[c + 8] - m_new);
                ps += p;
                p1[c] = (_Float16)p;
            }
            *(f16x8*)&P_lds[r][cs]     = p0;
            *(f16x8*)&P_lds[r][cs + 8] = p1;
            ps += __shfl_xor(ps, 1);
            ps += __shfl_xor(ps, 2);
            ps += __shfl_xor(ps, 4);
            if ((t & 7) == 0) {
                float al = __expf(m_old - m_new);
                alpha_lds[r] = al;
                l_lds[r] = l_lds[r] * al + ps;
                m_lds[r] = m_new;
            }
        }
        __syncthreads();

        // ---- rescale O by alpha, then PV: wave (qg,kc) owns d-cols kc*128..+128
#pragma unroll
        for (int mi = 0; mi < 2; mi++)
#pragma unroll
            for (int j = 0; j < 4; j++) {
                float al = alpha_lds[qg * 32 + mi * 16 + lq + j];
#pragma unroll
                for (int ni = 0; ni < 8; ni++) oacc[mi][ni][j] *= al;
            }

        for (int ks = 0; ks < 4; ks++) {
            f16x8 pa[2], vb[8];
#pragma unroll
            for (int mi = 0; mi < 2; mi++)
                pa[mi] = *(const f16x8*)&P_lds[qg * 32 + mi * 16 + lr][ks * 32 + lk];
#pragma unroll
            for (int ni = 0; ni < 8; ni++)
                vb[ni] = *(const f16x8*)(vp + (size_t)(kc * 128 + ni * 16 + lr) * S_ + kv0 + ks * 32 + lk);
#pragma unroll
            for (int mi = 0; mi < 2; mi++)
#pragma unroll
                for (int ni = 0; ni < 8; ni++)
                    oacc[mi][ni] = __builtin_amdgcn_mfma_f32_16x16x32_f16(pa[mi], vb[ni], oacc[mi][ni], 0, 0, 0);
        }
        __syncthreads();
    }

    // ---- normalize and store fp32 output
#pragma unroll
    for (int mi = 0; mi < 2; mi++)
#pragma unroll
        for (int j = 0; j < 4; j++) {
            int row = qg * 32 + mi * 16 + lq + j;
            float rl = 1.f / l_lds[row];
#pragma unroll
            for (int ni = 0; ni < 8; ni++) {
                int col = kc * 128 + ni * 16 + lr;
                out[((size_t)b * S_ + qb + row) * D_ + col] = oacc[mi][ni][j] * rl;
            }
        }
}

// ---------------------------------------------------------------------------
extern "C" void kernel_launch(void* const* d_in, const int* in_sizes, int n_in,
                              void* d_out, int out_size, void* d_ws, size_t ws_size,
                              hipStream_t stream) {
    const float* Q  = (const float*)d_in[0];
    const float* K  = (const float*)d_in[1];
    const float* V  = (const float*)d_in[2];
    const float* Wq = (const float*)d_in[3];
    const float* bq = (const float*)d_in[4];
    const float* Wk = (const float*)d_in[5];
    const float* bk = (const float*)d_in[6];
    const float* Wv = (const float*)d_in[7];
    const float* bv = (const float*)d_in[8];
    float* out = (float*)d_out;

    char* ws = (char*)d_ws;
    _Float16* w_ws = (_Float16*)ws;                                  // 3*512*512
    _Float16* q_ws = (_Float16*)(ws + 3ull * 512 * 512 * 2);         // [8][2048][512]
    _Float16* k_ws = q_ws + 8ull * 2048 * 512;                       // [8][2048][512]
    _Float16* v_ws = k_ws + 8ull * 2048 * 512;                       // [8][512][2048] (transposed)

    wconv_kernel<<<dim3(1024, 3), 256, 0, stream>>>(Wq, Wk, Wv, w_ws);
    proj_kernel<<<dim3(128, 4, 3), 256, 0, stream>>>(Q, K, V, w_ws, bq, bk, bv, q_ws, k_ws, v_ws);
    attn_kernel<<<dim3(256), 512, 0, stream>>>(q_ws, k_ws, v_ws, out);
}